// Round 3
// baseline (143.328 us; speedup 1.0000x reference)
//
#include <hip/hip_runtime.h>
#include <hip/hip_bf16.h>

#define BATCH   32
#define IN_DIM  2048
#define OUT_DIM 2048
#define ZDIM    64
#define NNZ     209715
#define KPB     128   // k's per compute block (256 threads = 128 k x 2 batch-halves)

// ---------------- workspace layout (byte offsets, 64B-aligned) ----------------
// cnt : int[2048]              @ 0
// rp  : int[2049]              @ 8192
// cur : int[2048]              @ 16448
// xT  : float[2048*32]         @ 24640   (x transposed: xT[i*32+b])
// E   : bf16[NNZ*32]           @ 286784  (E[pos*32+b] = e[b,k(pos)] * x[b,in_idx])
#define OFF_CNT 0
#define OFF_RP  8192
#define OFF_CUR 16448
#define OFF_XT  24640
#define OFF_E   286784
#define WS_NEEDED (OFF_E + (size_t)NNZ * BATCH * sizeof(__hip_bfloat16))

// ---- stage 1: histogram of out_idx + transpose x into xT ----
__global__ __launch_bounds__(256) void hist_kernel(
    const int* __restrict__ out_idx, const float* __restrict__ x,
    int* __restrict__ cnt, float* __restrict__ xT)
{
    const int k = blockIdx.x * 256 + threadIdx.x;
    if (k < NNZ) atomicAdd(&cnt[out_idx[k]], 1);
    if (k < BATCH * IN_DIM) {
        const int b = k >> 11;        // /2048
        const int i = k & 2047;       // %2048
        xT[i * BATCH + b] = x[k];
    }
}

// ---- stage 2: exclusive scan of 2048 bins -> rp[2049], cur[2048] ----
__global__ __launch_bounds__(1024) void scan_kernel(
    const int* __restrict__ cnt, int* __restrict__ rp, int* __restrict__ cur)
{
    __shared__ int s[1024];
    const int t = threadIdx.x;
    const int c0 = cnt[2 * t], c1 = cnt[2 * t + 1];
    const int pair = c0 + c1;
    int val = pair;
    s[t] = val;
    __syncthreads();
    for (int off = 1; off < 1024; off <<= 1) {
        const int add = (t >= off) ? s[t - off] : 0;
        __syncthreads();
        val += add;
        s[t] = val;
        __syncthreads();
    }
    const int ex = val - pair;  // exclusive prefix over pairs
    rp[2 * t] = ex;          cur[2 * t] = ex;
    rp[2 * t + 1] = ex + c0; cur[2 * t + 1] = ex + c0;
    if (t == 1023) rp[2048] = val;   // == NNZ
}

// ---- stage 3: per-k hypernet eval, fold in x, write bf16 to CSR slot ----
// 256 threads = 128 k's x 2 batch-halves. z read via wave-uniform loads
// (no lane dependence -> scalar s_load path, frees LDS/VMEM pipes).
__global__ __launch_bounds__(256) void compute_kernel(
    const float* __restrict__ z, const float* __restrict__ W,
    const float* __restrict__ bn, const int* __restrict__ in_idx,
    const int* __restrict__ out_idx, const float* __restrict__ xT,
    int* __restrict__ cur, __hip_bfloat16* __restrict__ E)
{
    __shared__ int posArr[KPB];
    const int t    = threadIdx.x;
    const int kl   = t & (KPB - 1);
    const int half = t >> 7;                 // 0 or 1 -> batches [0,16) / [16,32)
    const int k    = blockIdx.x * KPB + kl;
    const bool valid = (k < NNZ);

    int ii = 0;
    float bk = 0.f;
    if (valid) {
        ii = in_idx[k];
        bk = bn[k];
        if (half == 0) {
            const int oi = out_idx[k];
            posArr[kl] = atomicAdd(&cur[oi], 1);   // one slot per k
        }
    }
    __syncthreads();
    if (!valid) return;
    const int pos = posArr[kl];
    const int b0  = half * 16;

    // W column (64 rows), coalesced across lanes (consecutive k).
    float w[ZDIM];
    #pragma unroll
    for (int j = 0; j < ZDIM; ++j)
        w[j] = W[(size_t)j * NNZ + k];

    // x values for this k: 16 consecutive floats, 4 line-touches per lane.
    float4 xr[4];
    {
        const float4* xv = reinterpret_cast<const float4*>(xT + (size_t)ii * BATCH + b0);
        #pragma unroll
        for (int q = 0; q < 4; ++q) xr[q] = xv[q];
    }

    __hip_bfloat16 tmp[16];
    #pragma unroll
    for (int bb = 0; bb < 16; ++bb) {
        const int b = b0 + bb;
        float acc = bk;
        const float4* zr = reinterpret_cast<const float4*>(z + b * ZDIM);
        #pragma unroll
        for (int j4 = 0; j4 < ZDIM / 4; ++j4) {
            const float4 zz = zr[j4];          // wave-uniform -> s_load_dwordx4
            acc = fmaf(zz.x, w[4 * j4 + 0], acc);
            acc = fmaf(zz.y, w[4 * j4 + 1], acc);
            acc = fmaf(zz.z, w[4 * j4 + 2], acc);
            acc = fmaf(zz.w, w[4 * j4 + 3], acc);
        }
        tmp[bb] = __float2bfloat16(acc * reinterpret_cast<const float*>(xr)[bb]);
    }

    // 32B store (16 bf16) into this k's slot half.
    uint4* dst = reinterpret_cast<uint4*>(E + (size_t)pos * BATCH + b0);
    const uint4* src = reinterpret_cast<const uint4*>(tmp);
    dst[0] = src[0];
    dst[1] = src[1];
}

// ---- stage 4: per-column segmented reduce, atomic-free ----
__global__ __launch_bounds__(256) void reduce_kernel(
    const __hip_bfloat16* __restrict__ E, const int* __restrict__ rp,
    float* __restrict__ out)
{
    const int wave = threadIdx.x >> 6;          // 4 waves/block
    const int lane = threadIdx.x & 63;
    const int o = blockIdx.x * 4 + wave;        // 512 blocks -> 2048 columns
    const int b = lane & 31;
    const int h = lane >> 5;
    const int s = rp[o], e = rp[o + 1];
    float sum = 0.f;
    for (int p = s + h; p < e; p += 2)          // 64 lanes read 128B contiguous
        sum += __bfloat162float(E[(size_t)p * BATCH + b]);
    sum += __shfl_down(sum, 32);
    if (h == 0) out[b * OUT_DIM + o] = sum;
}

// ---- round-1 fallback (only if ws_size is too small) ----
__global__ __launch_bounds__(256) void hyper_scatter_kernel(
    const float* __restrict__ x, const float* __restrict__ z,
    const float* __restrict__ W, const float* __restrict__ bn,
    const int* __restrict__ in_idx, const int* __restrict__ out_idx,
    float* __restrict__ out)
{
    __shared__ float zs[BATCH * ZDIM];
    const int tid = threadIdx.x;
    {
        const float4* zg  = reinterpret_cast<const float4*>(z);
        float4*       zsv = reinterpret_cast<float4*>(zs);
        zsv[tid]       = zg[tid];
        zsv[tid + 256] = zg[tid + 256];
    }
    __syncthreads();
    const int k = blockIdx.x * 256 + tid;
    if (k >= NNZ) return;
    float w[ZDIM];
    #pragma unroll
    for (int j = 0; j < ZDIM; ++j) w[j] = W[(size_t)j * NNZ + k];
    const float bk = bn[k];
    const int ii = in_idx[k], oi = out_idx[k];
    const float4* zv = reinterpret_cast<const float4*>(zs);
    #pragma unroll
    for (int b = 0; b < BATCH; ++b) {
        float e = bk;
        #pragma unroll
        for (int j4 = 0; j4 < ZDIM / 4; ++j4) {
            const float4 zz = zv[b * (ZDIM / 4) + j4];
            e = fmaf(zz.x, w[j4 * 4 + 0], e);
            e = fmaf(zz.y, w[j4 * 4 + 1], e);
            e = fmaf(zz.z, w[j4 * 4 + 2], e);
            e = fmaf(zz.w, w[j4 * 4 + 3], e);
        }
        atomicAdd(&out[b * OUT_DIM + oi], e * x[b * IN_DIM + ii]);
    }
}

extern "C" void kernel_launch(void* const* d_in, const int* in_sizes, int n_in,
                              void* d_out, int out_size, void* d_ws, size_t ws_size,
                              hipStream_t stream) {
    const float* x       = (const float*)d_in[0];
    const float* z       = (const float*)d_in[1];
    const float* W       = (const float*)d_in[2];
    const float* bn      = (const float*)d_in[3];
    const int*   in_idx  = (const int*)d_in[4];
    const int*   out_idx = (const int*)d_in[5];
    float*       out     = (float*)d_out;

    if (ws_size < WS_NEEDED) {
        hipMemsetAsync(out, 0, (size_t)BATCH * OUT_DIM * sizeof(float), stream);
        const int grid = (NNZ + 255) / 256;
        hyper_scatter_kernel<<<grid, 256, 0, stream>>>(x, z, W, bn, in_idx, out_idx, out);
        return;
    }

    char* ws = (char*)d_ws;
    int*            cnt = (int*)(ws + OFF_CNT);
    int*            rp  = (int*)(ws + OFF_RP);
    int*            cur = (int*)(ws + OFF_CUR);
    float*          xT  = (float*)(ws + OFF_XT);
    __hip_bfloat16* E   = (__hip_bfloat16*)(ws + OFF_E);

    hipMemsetAsync(cnt, 0, 2048 * sizeof(int), stream);

    const int grid1 = (NNZ + 255) / 256;          // 820 (also covers x transpose)
    hist_kernel<<<grid1, 256, 0, stream>>>(out_idx, x, cnt, xT);
    scan_kernel<<<1, 1024, 0, stream>>>(cnt, rp, cur);
    const int grid3 = (NNZ + KPB - 1) / KPB;      // 1639
    compute_kernel<<<grid3, 256, 0, stream>>>(z, W, bn, in_idx, out_idx, xT, cur, E);
    reduce_kernel<<<OUT_DIM / 4, 256, 0, stream>>>(E, rp, out);
}

// Round 4
// 117.927 us; speedup vs baseline: 1.2154x; 1.2154x over previous
//
#include <hip/hip_runtime.h>
#include <hip/hip_bf16.h>

#define BATCH   32
#define IN_DIM  2048
#define OUT_DIM 2048
#define ZDIM    64
#define NNZ     209715

// ---------------- workspace layout (byte offsets, 64B-aligned) ----------------
// cnt : int[2048]              @ 0
// rp  : int[2049]              @ 8192
// cur : int[2048]              @ 16448
// xT  : float[2048*32]         @ 24640   (x transposed: xT[i*32+b])
// E   : bf16[NNZ*32]           @ 286784  (E[pos*32+b] = e[b,k(pos)] * x[b,in_idx])
#define OFF_CNT 0
#define OFF_RP  8192
#define OFF_CUR 16448
#define OFF_XT  24640
#define OFF_E   286784
#define WS_NEEDED (OFF_E + (size_t)NNZ * BATCH * sizeof(__hip_bfloat16))

// ---- stage 1: histogram of out_idx + transpose x into xT ----
__global__ __launch_bounds__(256) void hist_kernel(
    const int* __restrict__ out_idx, const float* __restrict__ x,
    int* __restrict__ cnt, float* __restrict__ xT)
{
    const int k = blockIdx.x * 256 + threadIdx.x;
    if (k < NNZ) atomicAdd(&cnt[out_idx[k]], 1);
    if (k < BATCH * IN_DIM) {
        const int b = k >> 11;        // /2048
        const int i = k & 2047;       // %2048
        xT[i * BATCH + b] = x[k];
    }
}

// ---- stage 2: exclusive scan of 2048 bins -> rp[2049], cur[2048] ----
__global__ __launch_bounds__(1024) void scan_kernel(
    const int* __restrict__ cnt, int* __restrict__ rp, int* __restrict__ cur)
{
    __shared__ int s[1024];
    const int t = threadIdx.x;
    const int c0 = cnt[2 * t], c1 = cnt[2 * t + 1];
    const int pair = c0 + c1;
    int val = pair;
    s[t] = val;
    __syncthreads();
    for (int off = 1; off < 1024; off <<= 1) {
        const int add = (t >= off) ? s[t - off] : 0;
        __syncthreads();
        val += add;
        s[t] = val;
        __syncthreads();
    }
    const int ex = val - pair;  // exclusive prefix over pairs
    rp[2 * t] = ex;          cur[2 * t] = ex;
    rp[2 * t + 1] = ex + c0; cur[2 * t + 1] = ex + c0;
    if (t == 1023) rp[2048] = val;   // == NNZ
}

// ---- stage 3: one thread per k, all 32 batches ----
// z addresses are (uniform arg + compile-time const) after full unroll ->
// compiler must emit s_load on the SCALAR pipe; VALU sees only the 2048 FMAs.
__global__ __launch_bounds__(256) void compute_kernel(
    const float* __restrict__ z, const float* __restrict__ W,
    const float* __restrict__ bn, const int* __restrict__ in_idx,
    const int* __restrict__ out_idx, const float* __restrict__ xT,
    int* __restrict__ cur, __hip_bfloat16* __restrict__ E)
{
    const int k = blockIdx.x * 256 + threadIdx.x;
    if (k >= NNZ) return;

    const int oi  = out_idx[k];
    const int pos = atomicAdd(&cur[oi], 1);   // latency hides under the FMAs
    const int ii  = in_idx[k];
    const float bk = bn[k];

    // W column (64 rows), coalesced across lanes (consecutive k).
    float w[ZDIM];
    #pragma unroll
    for (int j = 0; j < ZDIM; ++j)
        w[j] = W[(size_t)j * NNZ + k];

    float acc[BATCH];
    #pragma unroll
    for (int b = 0; b < BATCH; ++b) {
        float a = bk;
        const float4* zr = reinterpret_cast<const float4*>(z + b * ZDIM);
        #pragma unroll
        for (int j4 = 0; j4 < ZDIM / 4; ++j4) {
            const float4 zz = zr[j4];       // provably uniform -> s_load
            a = fmaf(zz.x, w[4 * j4 + 0], a);
            a = fmaf(zz.y, w[4 * j4 + 1], a);
            a = fmaf(zz.z, w[4 * j4 + 2], a);
            a = fmaf(zz.w, w[4 * j4 + 3], a);
        }
        acc[b] = a;
    }

    // x values for this k: 128B contiguous (after FMAs to cut reg pressure).
    float xr[BATCH];
    {
        const float4* xv = reinterpret_cast<const float4*>(xT + (size_t)ii * BATCH);
        #pragma unroll
        for (int q = 0; q < BATCH / 4; ++q)
            reinterpret_cast<float4*>(xr)[q] = xv[q];
    }

    __hip_bfloat16 tmp[BATCH];
    #pragma unroll
    for (int b = 0; b < BATCH; ++b)
        tmp[b] = __float2bfloat16(acc[b] * xr[b]);

    // 64B store into this k's CSR slot.
    uint4* dst = reinterpret_cast<uint4*>(E + (size_t)pos * BATCH);
    const uint4* src = reinterpret_cast<const uint4*>(tmp);
    #pragma unroll
    for (int q = 0; q < 4; ++q) dst[q] = src[q];
}

// ---- stage 4: per-column segmented reduce, vectorized, atomic-free ----
// One wave per output column o. Lane reads 8 bf16 (16B): 16 rows/iter.
__global__ __launch_bounds__(256) void reduce_kernel(
    const __hip_bfloat16* __restrict__ E, const int* __restrict__ rp,
    float* __restrict__ out)
{
    const int wave = threadIdx.x >> 6;          // 4 waves/block
    const int lane = threadIdx.x & 63;
    const int o = blockIdx.x * 4 + wave;        // 512 blocks -> 2048 columns
    const int r  = lane >> 2;                   // 0..15 row-in-group
    const int bg = lane & 3;                    // b-octet: b = bg*8 .. bg*8+7
    const int s = rp[o], e = rp[o + 1];

    float acc[8];
    #pragma unroll
    for (int q = 0; q < 8; ++q) acc[q] = 0.f;

    for (int p = s + r; p < e; p += 16) {
        const uint4 v = *reinterpret_cast<const uint4*>(E + (size_t)p * BATCH + bg * 8);
        const unsigned u[4] = {v.x, v.y, v.z, v.w};
        #pragma unroll
        for (int q = 0; q < 4; ++q) {
            const unsigned lo = (u[q] & 0xFFFFu) << 16;
            const unsigned hi = u[q] & 0xFFFF0000u;
            acc[2 * q]     += __uint_as_float(lo);
            acc[2 * q + 1] += __uint_as_float(hi);
        }
    }

    // reduce over r (lanes stride 4): xor 4,8,16,32
    #pragma unroll
    for (int d = 4; d < 64; d <<= 1) {
        #pragma unroll
        for (int q = 0; q < 8; ++q)
            acc[q] += __shfl_xor(acc[q], d);
    }

    if (lane < 4) {
        #pragma unroll
        for (int q = 0; q < 8; ++q)
            out[(bg * 8 + q) * OUT_DIM + o] = acc[q];
    }
}

// ---- round-1 fallback (only if ws_size is too small) ----
__global__ __launch_bounds__(256) void hyper_scatter_kernel(
    const float* __restrict__ x, const float* __restrict__ z,
    const float* __restrict__ W, const float* __restrict__ bn,
    const int* __restrict__ in_idx, const int* __restrict__ out_idx,
    float* __restrict__ out)
{
    __shared__ float zs[BATCH * ZDIM];
    const int tid = threadIdx.x;
    {
        const float4* zg  = reinterpret_cast<const float4*>(z);
        float4*       zsv = reinterpret_cast<float4*>(zs);
        zsv[tid]       = zg[tid];
        zsv[tid + 256] = zg[tid + 256];
    }
    __syncthreads();
    const int k = blockIdx.x * 256 + tid;
    if (k >= NNZ) return;
    float w[ZDIM];
    #pragma unroll
    for (int j = 0; j < ZDIM; ++j) w[j] = W[(size_t)j * NNZ + k];
    const float bk = bn[k];
    const int ii = in_idx[k], oi = out_idx[k];
    const float4* zv = reinterpret_cast<const float4*>(zs);
    #pragma unroll
    for (int b = 0; b < BATCH; ++b) {
        float e = bk;
        #pragma unroll
        for (int j4 = 0; j4 < ZDIM / 4; ++j4) {
            const float4 zz = zv[b * (ZDIM / 4) + j4];
            e = fmaf(zz.x, w[j4 * 4 + 0], e);
            e = fmaf(zz.y, w[j4 * 4 + 1], e);
            e = fmaf(zz.z, w[j4 * 4 + 2], e);
            e = fmaf(zz.w, w[j4 * 4 + 3], e);
        }
        atomicAdd(&out[b * OUT_DIM + oi], e * x[b * IN_DIM + ii]);
    }
}

extern "C" void kernel_launch(void* const* d_in, const int* in_sizes, int n_in,
                              void* d_out, int out_size, void* d_ws, size_t ws_size,
                              hipStream_t stream) {
    const float* x       = (const float*)d_in[0];
    const float* z       = (const float*)d_in[1];
    const float* W       = (const float*)d_in[2];
    const float* bn      = (const float*)d_in[3];
    const int*   in_idx  = (const int*)d_in[4];
    const int*   out_idx = (const int*)d_in[5];
    float*       out     = (float*)d_out;

    if (ws_size < WS_NEEDED) {
        hipMemsetAsync(out, 0, (size_t)BATCH * OUT_DIM * sizeof(float), stream);
        const int grid = (NNZ + 255) / 256;
        hyper_scatter_kernel<<<grid, 256, 0, stream>>>(x, z, W, bn, in_idx, out_idx, out);
        return;
    }

    char* ws = (char*)d_ws;
    int*            cnt = (int*)(ws + OFF_CNT);
    int*            rp  = (int*)(ws + OFF_RP);
    int*            cur = (int*)(ws + OFF_CUR);
    float*          xT  = (float*)(ws + OFF_XT);
    __hip_bfloat16* E   = (__hip_bfloat16*)(ws + OFF_E);

    hipMemsetAsync(cnt, 0, 2048 * sizeof(int), stream);

    const int grid1 = (NNZ + 255) / 256;          // 820 (also covers x transpose)
    hist_kernel<<<grid1, 256, 0, stream>>>(out_idx, x, cnt, xT);
    scan_kernel<<<1, 1024, 0, stream>>>(cnt, rp, cur);
    compute_kernel<<<grid1, 256, 0, stream>>>(z, W, bn, in_idx, out_idx, xT, cur, E);
    reduce_kernel<<<OUT_DIM / 4, 256, 0, stream>>>(E, rp, out);
}

// Round 5
// 59.208 us; speedup vs baseline: 2.4208x; 1.9918x over previous
//
#include <hip/hip_runtime.h>
#include <hip/hip_bf16.h>

#define BATCH   32
#define IN_DIM  2048
#define OUT_DIM 2048
#define ZDIM    64
#define NNZ     209715
#define CAP     160                       // max nnz per output col (mean 102.4, +5.7 sigma)
#define TILES   ((NNZ + 15) / 16)         // 13108
#define TPW     4                         // 16-k tiles per wave
#define CWAVES  ((TILES + TPW - 1) / TPW) // 3277
#define CBLOCKS ((CWAVES + 3) / 4)        // 820

typedef __attribute__((ext_vector_type(8))) short bf16x8;
typedef __attribute__((ext_vector_type(4))) float f32x4;

// ---- bucket-mode workspace (preferred): 21.3 MB ----
#define B_OFF_CUR 0
#define B_OFF_XT  8192
#define B_OFF_E   (8192 + 262144)                      // 270336, 16B aligned
#define B_WS_NEEDED (B_OFF_E + (size_t)OUT_DIM * CAP * BATCH * 2)

// ---- CSR-mode workspace (fallback): 13.7 MB (proven to fit in round 2-4) ----
#define C_OFF_CNT 0
#define C_OFF_RP  8192
#define C_OFF_CUR 16448
#define C_OFF_XT  24640
#define C_OFF_E   286784
#define C_WS_NEEDED (C_OFF_E + (size_t)NNZ * BATCH * 2)

__device__ __forceinline__ short f2bf(float f) {      // RNE f32 -> bf16
    unsigned u = __float_as_uint(f);
    u += 0x7fffu + ((u >> 16) & 1u);
    return (short)(u >> 16);
}

// ---- prep (bucket): zero cur + transpose x -> xT[i*32+b]; grid = 256 blocks ----
__global__ __launch_bounds__(256) void prep_bucket(
    const float* __restrict__ x, float* __restrict__ xT, int* __restrict__ cur)
{
    const int idx = blockIdx.x * 256 + threadIdx.x;   // exactly 65536
    if (idx < OUT_DIM) cur[idx] = 0;
    const int b = idx >> 11;
    const int i = idx & 2047;
    xT[i * BATCH + b] = x[idx];
}

// ---- CSR stage 1: histogram + transpose ----
__global__ __launch_bounds__(256) void hist_kernel(
    const int* __restrict__ out_idx, const float* __restrict__ x,
    int* __restrict__ cnt, float* __restrict__ xT)
{
    const int k = blockIdx.x * 256 + threadIdx.x;
    if (k < NNZ) atomicAdd(&cnt[out_idx[k]], 1);
    if (k < BATCH * IN_DIM) {
        const int b = k >> 11;
        const int i = k & 2047;
        xT[i * BATCH + b] = x[k];
    }
}

// ---- CSR stage 2: exclusive scan -> rp[2049], cur[2048] ----
__global__ __launch_bounds__(1024) void scan_kernel(
    const int* __restrict__ cnt, int* __restrict__ rp, int* __restrict__ cur)
{
    __shared__ int s[1024];
    const int t = threadIdx.x;
    const int c0 = cnt[2 * t], c1 = cnt[2 * t + 1];
    const int pair = c0 + c1;
    int val = pair;
    s[t] = val;
    __syncthreads();
    for (int off = 1; off < 1024; off <<= 1) {
        const int add = (t >= off) ? s[t - off] : 0;
        __syncthreads();
        val += add;
        s[t] = val;
        __syncthreads();
    }
    const int ex = val - pair;
    rp[2 * t] = ex;          cur[2 * t] = ex;
    rp[2 * t + 1] = ex + c0; cur[2 * t + 1] = ex + c0;
    if (t == 1023) rp[2048] = val;
}

// ---- main compute: MFMA GEMM E[k,b] = (W^T z^T)[k,b], fold x, scatter rows ----
// MODE 0: bucket rows (oi*CAP + p), MODE 1: CSR rows (p, cur pre-filled with rp)
template <int MODE>
__global__ __launch_bounds__(256) void compute_mfma(
    const float* __restrict__ z, const float* __restrict__ W,
    const float* __restrict__ bn, const int* __restrict__ in_idx,
    const int* __restrict__ out_idx, const float* __restrict__ xT,
    int* __restrict__ cur, short* __restrict__ E)
{
    const int lane = threadIdx.x & 63;
    const int m    = lane & 15;            // A-row (k in tile) / B,C col (b)
    const int hi   = lane >> 4;            // k-slice group for inputs
    const int gw   = blockIdx.x * 4 + (threadIdx.x >> 6);

    // B-fragments: zf[bt][jt], held in VGPRs for the WHOLE kernel (zero refetch).
    // B[j, b] = z[b][j]; b = bt*16 + m, j = jt*32 + hi*8 + e  (contiguous in e).
    bf16x8 zf[2][2];
    #pragma unroll
    for (int bt = 0; bt < 2; ++bt)
        #pragma unroll
        for (int jt = 0; jt < 2; ++jt) {
            const float* zp = z + (bt * 16 + m) * ZDIM + jt * 32 + hi * 8;
            const float4 a = *reinterpret_cast<const float4*>(zp);
            const float4 c = *reinterpret_cast<const float4*>(zp + 4);
            union { bf16x8 v; short s[8]; } u;
            u.s[0] = f2bf(a.x); u.s[1] = f2bf(a.y); u.s[2] = f2bf(a.z); u.s[3] = f2bf(a.w);
            u.s[4] = f2bf(c.x); u.s[5] = f2bf(c.y); u.s[6] = f2bf(c.z); u.s[7] = f2bf(c.w);
            zf[bt][jt] = u.v;
        }

    #pragma unroll
    for (int tt = 0; tt < TPW; ++tt) {
        const int t = gw * TPW + tt;
        if (t >= TILES) break;             // uniform across the wave
        const int k0 = t * 16;

        // A-fragment: A[m, j] = W[j][k0+m]; 16 coalesced dword loads (64B segments)
        const int kA = (k0 + m < NNZ) ? (k0 + m) : (NNZ - 1);
        const float* wp = W + (size_t)(hi * 8) * NNZ + kA;
        float wv[16];
        #pragma unroll
        for (int e = 0; e < 8; ++e) wv[e]     = wp[(size_t)e * NNZ];
        #pragma unroll
        for (int e = 0; e < 8; ++e) wv[8 + e] = wp[(size_t)(32 + e) * NNZ];

        // per-k metadata + slot (lanes 0..15), latency hides under cvt+mfma
        int rowL = -1, iiL = 0; float bnL = 0.f;
        if (lane < 16) {
            const int kk = k0 + lane;
            if (kk < NNZ) {
                iiL = in_idx[kk];
                bnL = bn[kk];
                const int oi = out_idx[kk];
                const int p  = atomicAdd(&cur[oi], 1);
                if (MODE == 0) rowL = (p < CAP) ? (oi * CAP + p) : -1;
                else           rowL = p;
            }
        }

        union { bf16x8 v; short s[8]; } a0, a1;
        #pragma unroll
        for (int e = 0; e < 8; ++e) { a0.s[e] = f2bf(wv[e]); a1.s[e] = f2bf(wv[8 + e]); }

        f32x4 acc0 = {0.f, 0.f, 0.f, 0.f};
        f32x4 acc1 = {0.f, 0.f, 0.f, 0.f};
        acc0 = __builtin_amdgcn_mfma_f32_16x16x32_bf16(a0.v, zf[0][0], acc0, 0, 0, 0);
        acc0 = __builtin_amdgcn_mfma_f32_16x16x32_bf16(a1.v, zf[0][1], acc0, 0, 0, 0);
        acc1 = __builtin_amdgcn_mfma_f32_16x16x32_bf16(a0.v, zf[1][0], acc1, 0, 0, 0);
        acc1 = __builtin_amdgcn_mfma_f32_16x16x32_bf16(a1.v, zf[1][1], acc1, 0, 0, 0);

        // epilogue: lane holds C rows k = k0 + hi*4 + r, col b = bt*16 + m
        #pragma unroll
        for (int r = 0; r < 4; ++r) {
            const int src  = hi * 4 + r;
            const int row  = __shfl(rowL, src);
            const int ii   = __shfl(iiL, src);
            const float bb = __shfl(bnL, src);
            if (row >= 0) {
                const float x0 = xT[ii * BATCH + m];        // 64B per 16-lane group
                const float x1 = xT[ii * BATCH + 16 + m];
                short* Ep = E + (size_t)row * BATCH;
                Ep[m]      = f2bf((acc0[r] + bb) * x0);     // 32B coalesced per row-half
                Ep[16 + m] = f2bf((acc1[r] + bb) * x1);
            }
        }
    }
}

// ---- segmented reduce over E rows, vectorized, atomic-free ----
// MODE 0: seg = cur (counts), rows at o*CAP; MODE 1: seg = rp (CSR offsets)
template <int MODE>
__global__ __launch_bounds__(256) void reduce_bf16(
    const short* __restrict__ E, const int* __restrict__ seg,
    float* __restrict__ out)
{
    const int wave = threadIdx.x >> 6;
    const int lane = threadIdx.x & 63;
    const int o = blockIdx.x * 4 + wave;        // 512 blocks -> 2048 columns
    const int r  = lane >> 2;                   // 0..15 row-in-group
    const int bg = lane & 3;                    // b-octet
    int s, e;
    if (MODE == 0) {
        s = o * CAP;
        int c = seg[o]; if (c > CAP) c = CAP;
        e = s + c;
    } else {
        s = seg[o]; e = seg[o + 1];
    }

    float acc[8];
    #pragma unroll
    for (int q = 0; q < 8; ++q) acc[q] = 0.f;

    for (int p = s + r; p < e; p += 16) {
        const uint4 v = *reinterpret_cast<const uint4*>(E + (size_t)p * BATCH + bg * 8);
        const unsigned u[4] = {v.x, v.y, v.z, v.w};
        #pragma unroll
        for (int q = 0; q < 4; ++q) {
            acc[2 * q]     += __uint_as_float((u[q] & 0xFFFFu) << 16);
            acc[2 * q + 1] += __uint_as_float(u[q] & 0xFFFF0000u);
        }
    }

    #pragma unroll
    for (int d = 4; d < 64; d <<= 1)
        #pragma unroll
        for (int q = 0; q < 8; ++q)
            acc[q] += __shfl_xor(acc[q], d);

    if (lane < 4)
        #pragma unroll
        for (int q = 0; q < 8; ++q)
            out[(bg * 8 + q) * OUT_DIM + o] = acc[q];
}

// ---- last-resort fallback: round-1 atomic scatter ----
__global__ __launch_bounds__(256) void hyper_scatter_kernel(
    const float* __restrict__ x, const float* __restrict__ z,
    const float* __restrict__ W, const float* __restrict__ bn,
    const int* __restrict__ in_idx, const int* __restrict__ out_idx,
    float* __restrict__ out)
{
    __shared__ float zs[BATCH * ZDIM];
    const int tid = threadIdx.x;
    {
        const float4* zg  = reinterpret_cast<const float4*>(z);
        float4*       zsv = reinterpret_cast<float4*>(zs);
        zsv[tid]       = zg[tid];
        zsv[tid + 256] = zg[tid + 256];
    }
    __syncthreads();
    const int k = blockIdx.x * 256 + tid;
    if (k >= NNZ) return;
    float w[ZDIM];
    #pragma unroll
    for (int j = 0; j < ZDIM; ++j) w[j] = W[(size_t)j * NNZ + k];
    const float bk = bn[k];
    const int ii = in_idx[k], oi = out_idx[k];
    const float4* zv = reinterpret_cast<const float4*>(zs);
    #pragma unroll
    for (int b = 0; b < BATCH; ++b) {
        float e = bk;
        #pragma unroll
        for (int j4 = 0; j4 < ZDIM / 4; ++j4) {
            const float4 zz = zv[b * (ZDIM / 4) + j4];
            e = fmaf(zz.x, w[j4 * 4 + 0], e);
            e = fmaf(zz.y, w[j4 * 4 + 1], e);
            e = fmaf(zz.z, w[j4 * 4 + 2], e);
            e = fmaf(zz.w, w[j4 * 4 + 3], e);
        }
        atomicAdd(&out[b * OUT_DIM + oi], e * x[b * IN_DIM + ii]);
    }
}

extern "C" void kernel_launch(void* const* d_in, const int* in_sizes, int n_in,
                              void* d_out, int out_size, void* d_ws, size_t ws_size,
                              hipStream_t stream) {
    const float* x       = (const float*)d_in[0];
    const float* z       = (const float*)d_in[1];
    const float* W       = (const float*)d_in[2];
    const float* bn      = (const float*)d_in[3];
    const int*   in_idx  = (const int*)d_in[4];
    const int*   out_idx = (const int*)d_in[5];
    float*       out     = (float*)d_out;
    char*        ws      = (char*)d_ws;

    if (ws_size >= B_WS_NEEDED) {
        // Bucket path: 3 dispatches, no hist/scan/memset.
        int*   cur = (int*)(ws + B_OFF_CUR);
        float* xT  = (float*)(ws + B_OFF_XT);
        short* E   = (short*)(ws + B_OFF_E);
        prep_bucket<<<(BATCH * IN_DIM) / 256, 256, 0, stream>>>(x, xT, cur);
        compute_mfma<0><<<CBLOCKS, 256, 0, stream>>>(z, W, bn, in_idx, out_idx, xT, cur, E);
        reduce_bf16<0><<<OUT_DIM / 4, 256, 0, stream>>>(E, cur, out);
    } else if (ws_size >= C_WS_NEEDED) {
        // CSR path (13.7 MB, known to fit).
        int*   cnt = (int*)(ws + C_OFF_CNT);
        int*   rp  = (int*)(ws + C_OFF_RP);
        int*   cur = (int*)(ws + C_OFF_CUR);
        float* xT  = (float*)(ws + C_OFF_XT);
        short* E   = (short*)(ws + C_OFF_E);
        hipMemsetAsync(cnt, 0, 2048 * sizeof(int), stream);
        const int grid1 = (NNZ + 255) / 256;
        hist_kernel<<<grid1, 256, 0, stream>>>(out_idx, x, cnt, xT);
        scan_kernel<<<1, 1024, 0, stream>>>(cnt, rp, cur);
        compute_mfma<1><<<CBLOCKS, 256, 0, stream>>>(z, W, bn, in_idx, out_idx, xT, cur, E);
        reduce_bf16<1><<<OUT_DIM / 4, 256, 0, stream>>>(E, rp, out);
    } else {
        hipMemsetAsync(out, 0, (size_t)BATCH * OUT_DIM * sizeof(float), stream);
        const int grid = (NNZ + 255) / 256;
        hyper_scatter_kernel<<<grid, 256, 0, stream>>>(x, z, W, bn, in_idx, out_idx, out);
    }
}